// Round 1
// baseline (392.803 us; speedup 1.0000x reference)
//
#include <hip/hip_runtime.h>

#define TB 256

// Problem constants
// B=16, C=64, L=16384, HOP=256, KS=3, DIL=3, KL=64, 2C=128

__device__ __forceinline__ float lrelu(float v) { return v > 0.0f ? v : 0.2f * v; }

__device__ __forceinline__ void fma4(float4& a, float s, const float4& w) {
    a.x = fmaf(s, w.x, a.x);
    a.y = fmaf(s, w.y, a.y);
    a.z = fmaf(s, w.z, a.z);
    a.w = fmaf(s, w.w, a.w);
}

__device__ __forceinline__ float glu_gate(float a, float t) {
    // sigmoid(a) * tanh(t), overflow-safe
    float sg = 1.0f / (1.0f + __expf(-a));
    float e  = __expf(-2.0f * t);
    float th = 2.0f / (1.0f + e) - 1.0f;
    return sg * th;
}

// LDS layout (floats):
//   region0 [0,16896):      xl[64][264]   (lrelu'd x tile)   -> later kl[64][3][64] (LVC weights, one half)
//   region1 [16896,33792):  wl[64][3][64] (conv weights)     -> later hl[64][264]   (h tile, cols 3..260 valid)
#define LDS_FLOATS (16896 + 16896)

__global__ __launch_bounds__(256, 1)
void fused_lvc_kernel(const float* __restrict__ x,
                      const float* __restrict__ kern,
                      const float* __restrict__ bias,
                      const float* __restrict__ conv_w,
                      const float* __restrict__ conv_b,
                      const float* __restrict__ kt,
                      float* __restrict__ out)
{
    __shared__ float lds[LDS_FLOATS];
    float* xl = lds;             // [64][264]
    float* kl = lds;             // [64][3][64] (aliases xl after conv)
    float* wl = lds + 16896;     // [64][3][64]
    float* hl = lds + 16896;     // [64][264]  (aliases wl after conv reads complete)

    const int tid = threadIdx.x;
    const int blk = blockIdx.x;       // 1024 = b*64 + f
    const int b = blk >> 6, f = blk & 63;
    const int t0 = f << 8;

    // ---------------- Phase A: stage lrelu(x) halo tile + conv weights ----------------
    {
        const float* xb = x + (b * 64) * 16384;
        for (int i4 = tid; i4 < 4224; i4 += TB) {          // 64 rows * 66 float4
            int ci = i4 / 66, p4 = (i4 % 66) << 2;
            int g = t0 - 4 + p4;                            // global time of first elem
            float4 v = make_float4(0.f, 0.f, 0.f, 0.f);
            if (g >= 0 && g < 16384)
                v = *(const float4*)(xb + ci * 16384 + g);
            v.x = lrelu(v.x); v.y = lrelu(v.y); v.z = lrelu(v.z); v.w = lrelu(v.w);
            *(float4*)(xl + ci * 264 + p4) = v;
        }
        // conv_w[co][ci][k] -> wl[ci][k][co] (coalesced global reads, scattered LDS writes; one-time)
        for (int i = tid; i < 12288; i += TB) {
            int co = i / 192, r = i % 192, ci = r / 3, k = r % 3;
            wl[ci * 192 + (k << 6) + co] = conv_w[i];
        }
    }
    __syncthreads();

    // ---------------- Phase B: dilated conv (dil=3, pad=3) + bias + lrelu ----------------
    // interior: thread (ug, cgrp): positions u = 4*ug+{0..3}, out-ch co = cgrp*16+{0..15}
    const int ug = tid & 63, cgrp = tid >> 6;
    float4 Wa[4][4];
    #pragma unroll
    for (int i = 0; i < 4; ++i)
        #pragma unroll
        for (int j = 0; j < 4; ++j) Wa[i][j] = make_float4(0.f, 0.f, 0.f, 0.f);

    for (int ci = 0; ci < 64; ++ci) {
        const float* xr = xl + ci * 264 + (ug << 2);
        float4 r0 = *(const float4*)(xr);
        float4 r1 = *(const float4*)(xr + 4);
        float4 r2 = *(const float4*)(xr + 8);
        float xt[12];
        xt[0]=r0.x; xt[1]=r0.y; xt[2]=r0.z; xt[3]=r0.w;
        xt[4]=r1.x; xt[5]=r1.y; xt[6]=r1.z; xt[7]=r1.w;
        xt[8]=r2.x; xt[9]=r2.y; xt[10]=r2.z; xt[11]=r2.w;
        const float* wr = wl + ci * 192 + (cgrp << 4);
        #pragma unroll
        for (int k = 0; k < 3; ++k) {
            float4 w0 = *(const float4*)(wr + (k << 6));
            float4 w1 = *(const float4*)(wr + (k << 6) + 4);
            float4 w2 = *(const float4*)(wr + (k << 6) + 8);
            float4 w3 = *(const float4*)(wr + (k << 6) + 12);
            #pragma unroll
            for (int i = 0; i < 4; ++i) {
                float xv = xt[i + 3 * k + 1];   // x pos = t0+u+3(k-1), tile col = u+3k+1
                fma4(Wa[i][0], xv, w0);
                fma4(Wa[i][1], xv, w1);
                fma4(Wa[i][2], xv, w2);
                fma4(Wa[i][3], xv, w3);
            }
        }
    }

    // border h values (positions t0-1 and t0+256), needed by LVC window; zero at sequence ends
    float bacc = 0.0f;
    int bco = 0, bcol = 0;
    const bool has_border = (tid < 128);
    if (has_border) {
        int e = tid >> 6;                 // 0: left (t0-1), 1: right (t0+256)
        bco = tid & 63;
        int bhi = e ? 257 : 0;
        bcol = bhi + 3;                   // hl column
        int pos = t0 - 1 + bhi;
        if (pos >= 0 && pos < 16384) {
            float acc = conv_b[bco];
            for (int ci = 0; ci < 64; ++ci) {
                #pragma unroll
                for (int k = 0; k < 3; ++k)
                    acc = fmaf(xl[ci * 264 + bhi + 3 * k], wl[ci * 192 + (k << 6) + bco], acc);
            }
            bacc = lrelu(acc);
        }
    }

    // bias + lrelu on interior accumulators (registers only)
    {
        const float* cb = conv_b + (cgrp << 4);
        #pragma unroll
        for (int j = 0; j < 4; ++j) {
            float4 c4 = *(const float4*)(cb + (j << 2));
            #pragma unroll
            for (int i = 0; i < 4; ++i) {
                Wa[i][j].x = lrelu(Wa[i][j].x + c4.x);
                Wa[i][j].y = lrelu(Wa[i][j].y + c4.y);
                Wa[i][j].z = lrelu(Wa[i][j].z + c4.z);
                Wa[i][j].w = lrelu(Wa[i][j].w + c4.w);
            }
        }
    }
    __syncthreads();   // all reads of xl & wl complete

    // write h tile (transpose acc in registers: 4 consecutive positions per store)
    {
        int colbase = (ug << 2) + 4;      // position t0+u stored at col u+4
        #pragma unroll
        for (int j = 0; j < 4; ++j) {
            int co0 = (cgrp << 4) + (j << 2);
            *(float4*)(hl + (co0 + 0) * 264 + colbase) =
                make_float4(Wa[0][j].x, Wa[1][j].x, Wa[2][j].x, Wa[3][j].x);
            *(float4*)(hl + (co0 + 1) * 264 + colbase) =
                make_float4(Wa[0][j].y, Wa[1][j].y, Wa[2][j].y, Wa[3][j].y);
            *(float4*)(hl + (co0 + 2) * 264 + colbase) =
                make_float4(Wa[0][j].z, Wa[1][j].z, Wa[2][j].z, Wa[3][j].z);
            *(float4*)(hl + (co0 + 3) * 264 + colbase) =
                make_float4(Wa[0][j].w, Wa[1][j].w, Wa[2][j].w, Wa[3][j].w);
        }
        if (has_border) hl[bco * 264 + bcol] = bacc;
    }

    // ---------------- Phase C: LVC (2 passes over GLU-paired channel halves) ----------------
    const int sg = tid & 63, ccg = tid >> 6;
    #pragma unroll 1
    for (int pass = 0; pass < 2; ++pass) {
        if (pass == 1) __syncthreads();   // pass-0 kl reads complete before overwrite
        // load this pass's LVC weights: kl[ci][k][j], j = 2*c' + gate, oc = pass*32 + c' + gate*64
        if (kt) {
            const float4* src = (const float4*)(kt + (blk * 2 + pass) * 12288);
            for (int i4 = tid; i4 < 3072; i4 += TB)
                *(float4*)(kl + (i4 << 2)) = src[i4];
        } else {
            const float* kb = kern + b * 1572864 + f;
            for (int i = tid; i < 12288; i += TB) {
                int ci = i / 192, r = i % 192, k = r >> 6, j = r & 63;
                int oc = (pass << 5) + (j >> 1) + ((j & 1) << 6);
                kl[i] = kb[ci * 24576 + oc * 192 + (k << 6)];
            }
        }
        __syncthreads();

        float4 A[4][4];
        #pragma unroll
        for (int i = 0; i < 4; ++i)
            #pragma unroll
            for (int m = 0; m < 4; ++m) A[i][m] = make_float4(0.f, 0.f, 0.f, 0.f);

        for (int ci = 0; ci < 64; ++ci) {
            const float* hr = hl + ci * 264 + (sg << 2);
            float4 r0 = *(const float4*)(hr);
            float4 r1 = *(const float4*)(hr + 4);
            float4 r2 = *(const float4*)(hr + 8);
            float ht[12];
            ht[0]=r0.x; ht[1]=r0.y; ht[2]=r0.z; ht[3]=r0.w;
            ht[4]=r1.x; ht[5]=r1.y; ht[6]=r1.z; ht[7]=r1.w;
            ht[8]=r2.x; ht[9]=r2.y; ht[10]=r2.z; ht[11]=r2.w;
            const float* kr = kl + ci * 192 + (ccg << 4);
            #pragma unroll
            for (int k = 0; k < 3; ++k) {
                float4 k0 = *(const float4*)(kr + (k << 6));
                float4 k1 = *(const float4*)(kr + (k << 6) + 4);
                float4 k2 = *(const float4*)(kr + (k << 6) + 8);
                float4 k3 = *(const float4*)(kr + (k << 6) + 12);
                #pragma unroll
                for (int i = 0; i < 4; ++i) {
                    float hv = ht[i + k + 3];   // h pos = t0+s+k-1, col = s+k+3
                    fma4(A[i][0], hv, k0);
                    fma4(A[i][1], hv, k1);
                    fma4(A[i][2], hv, k2);
                    fma4(A[i][3], hv, k3);
                }
            }
        }

        // epilogue: bias, GLU gate, residual, store
        const int cbase = (pass << 5) + (ccg << 3);
        const int t = t0 + (sg << 2);
        #pragma unroll
        for (int m = 0; m < 4; ++m) {
            int ca = cbase + 2 * m;
            float ba0 = bias[b * 8192 + ca * 64 + f];
            float bb0 = bias[b * 8192 + (ca + 64) * 64 + f];
            float ba1 = bias[b * 8192 + (ca + 1) * 64 + f];
            float bb1 = bias[b * 8192 + (ca + 65) * 64 + f];
            const float* xres = x + (b * 64 + ca) * 16384 + t;
            float4 res0 = *(const float4*)(xres);
            float4 res1 = *(const float4*)(xres + 16384);
            float4 o0, o1;
            o0.x = res0.x + glu_gate(A[0][m].x + ba0, A[0][m].y + bb0);
            o0.y = res0.y + glu_gate(A[1][m].x + ba0, A[1][m].y + bb0);
            o0.z = res0.z + glu_gate(A[2][m].x + ba0, A[2][m].y + bb0);
            o0.w = res0.w + glu_gate(A[3][m].x + ba0, A[3][m].y + bb0);
            o1.x = res1.x + glu_gate(A[0][m].z + ba1, A[0][m].w + bb1);
            o1.y = res1.y + glu_gate(A[1][m].z + ba1, A[1][m].w + bb1);
            o1.z = res1.z + glu_gate(A[2][m].z + ba1, A[2][m].w + bb1);
            o1.w = res1.w + glu_gate(A[3][m].z + ba1, A[3][m].w + bb1);
            float* ob = out + (b * 64 + ca) * 16384 + t;
            *(float4*)(ob) = o0;
            *(float4*)(ob + 16384) = o1;
        }
    }
}

// kernel[b][ci][oc][k][f] -> kt[b][f][h][ci][k][j], j = 2*c'+gate, oc = h*32 + c' + gate*64
__global__ __launch_bounds__(256, 2)
void kt_transpose_kernel(const float* __restrict__ kern, float* __restrict__ kt)
{
    __shared__ float tl[128 * 65];
    const int tid = threadIdx.x;
    const int blk = blockIdx.x;            // 3072 = ((b*64)+ci)*3 + k
    const int b = blk / 192, r = blk % 192, ci = r / 3, k = r % 3;
    const float* src = kern + b * 1572864 + ci * 24576 + (k << 6);
    for (int i4 = tid; i4 < 2048; i4 += TB) {      // 128 oc * 16 float4
        int oc = i4 >> 4, fi = (i4 & 15) << 2;
        float4 v = *(const float4*)(src + oc * 192 + fi);
        float* d = tl + oc * 65 + fi;
        d[0] = v.x; d[1] = v.y; d[2] = v.z; d[3] = v.w;
    }
    __syncthreads();
    for (int i = tid; i < 8192; i += TB) {
        int fh = i >> 6, j = i & 63;
        int h = fh & 1, fr = fh >> 1;
        int oc = (h << 5) + (j >> 1) + ((j & 1) << 6);
        kt[((b << 6) | fr) * 24576 + h * 12288 + (ci * 3 + k) * 64 + j] = tl[oc * 65 + fr];
    }
}

extern "C" void kernel_launch(void* const* d_in, const int* in_sizes, int n_in,
                              void* d_out, int out_size, void* d_ws, size_t ws_size,
                              hipStream_t stream)
{
    const float* x      = (const float*)d_in[0];
    const float* kern   = (const float*)d_in[1];
    const float* bias   = (const float*)d_in[2];
    const float* conv_w = (const float*)d_in[3];
    const float* conv_b = (const float*)d_in[4];
    float* out = (float*)d_out;

    const float* kt = nullptr;
    if (ws_size >= 100663296ULL) {     // 1024 * 24576 * 4 bytes
        kt_transpose_kernel<<<dim3(3072), dim3(TB), 0, stream>>>(kern, (float*)d_ws);
        kt = (const float*)d_ws;
    }
    fused_lvc_kernel<<<dim3(1024), dim3(TB), 0, stream>>>(x, kern, bias, conv_w, conv_b, kt, out);
}

// Round 2
// 134.058 us; speedup vs baseline: 2.9301x; 2.9301x over previous
//
#include <hip/hip_runtime.h>

#define TB 256

typedef __attribute__((ext_vector_type(8))) short short8;
typedef __attribute__((ext_vector_type(8))) unsigned short ushort8;
typedef __attribute__((ext_vector_type(4))) float f32x4;

// Problem constants: B=16, C=64, L=16384, HOP=256, KS=3, DIL=3, KL=64
// ws layout: ktf (bf16, fragment-linear LVC A) 50,331,648 B; wf (conv A) 24,576 B
#define KTF_BYTES 50331648ull
#define WS_NEED   (KTF_BYTES + 24576ull)

static __device__ __forceinline__ float lrelu(float v){ return v > 0.f ? v : 0.2f*v; }

static __device__ __forceinline__ unsigned int f2bf(float x){
    unsigned int u = __float_as_uint(x);
    u = u + 0x7FFFu + ((u >> 16) & 1u);      // RNE; inputs finite
    return u >> 16;
}

static __device__ __forceinline__ float glu_gate(float a, float t){
    float sg = 1.0f / (1.0f + __expf(-a));
    float e  = __expf(-2.0f * t);
    float th = 2.0f / (1.0f + e) - 1.0f;
    return sg * th;
}

// ---------------------------------------------------------------------------
// kern[b][ci][oc][k][f] -> ktf[(b*64+f)][mt0..7][kk0..5][lane0..63][j0..7] bf16
// A[m=oc][r=k*64+ci]; frag: lane holds row=lane&15, r = kk*32 + (lane>>4)*8 + j
// block = (b, ci2 in [0,32), k): covers ci = 2*ci2, 2*ci2+1
__global__ __launch_bounds__(256, 2)
void ktf_transpose(const float* __restrict__ kern, unsigned short* __restrict__ ktf)
{
    __shared__ unsigned short tl[2*128*66];   // [cl][oc][f pad 66]
    const int tid = threadIdx.x;
    const int blk = blockIdx.x;               // 1536 = b*96 + ci2*3 + k
    const int k   = blk % 3;
    const int ci2 = (blk / 3) % 32;
    const int b   = blk / 96;

    const float* src0 = kern + (size_t)b*1572864 + (size_t)ci2*2*24576 + k*64;
    for (int i4 = tid; i4 < 4096; i4 += TB) {          // 2ci * 128oc * 16 f4
        int cl = i4 >> 11, oc = (i4 >> 4) & 127, fq = i4 & 15;
        float4 v = *(const float4*)(src0 + cl*24576 + oc*192 + fq*4);
        unsigned int w0 = f2bf(v.x) | (f2bf(v.y) << 16);
        unsigned int w1 = f2bf(v.z) | (f2bf(v.w) << 16);
        unsigned int* d = (unsigned int*)(tl + (cl*128 + oc)*66 + fq*4);
        d[0] = w0; d[1] = w1;
    }
    __syncthreads();

    const int kk     = k*2 + (ci2 >> 4);
    const int lanehi = (ci2 >> 2) & 3;
    const int jj     = ci2 & 3;
    for (int it = 0; it < 32; ++it) {
        int u = tid + it*TB;                   // 8192 = 16 oclow * 8 mt * 64 f
        int oclow = u & 15, mt = (u >> 4) & 7, f = u >> 7;
        int oc = mt*16 + oclow;
        unsigned int lo = tl[oc*66 + f];
        unsigned int hi = tl[(128 + oc)*66 + f];
        size_t off = (size_t)(b*64 + f)*24576 + (size_t)(mt*6 + kk)*512
                   + (lanehi*16 + oclow)*8 + jj*2;
        *(unsigned int*)(ktf + off) = lo | (hi << 16);
    }
}

// conv_w[co][ci][k] -> wf[mt0..3][kk0..5][lane][j] bf16 (A[m=co][r=k*64+ci])
__global__ __launch_bounds__(256, 2)
void wf_prep(const float* __restrict__ conv_w, unsigned short* __restrict__ wf)
{
    int u = blockIdx.x*TB + threadIdx.x;       // 1536 units of 8 elems
    int frag = u >> 6, ln = u & 63;
    int mt = frag / 6, kk = frag % 6;
    int m = mt*16 + (ln & 15);
    ushort8 v;
    #pragma unroll
    for (int j = 0; j < 8; ++j) {
        int r = kk*32 + (ln >> 4)*8 + j;
        v[j] = (unsigned short)f2bf(conv_w[m*192 + (r & 63)*3 + (r >> 6)]);
    }
    *(ushort8*)(wf + (size_t)u*8) = v;
}

// ---------------------------------------------------------------------------
// LDS: xt[288 rows][64 ci] bf16 swizzled @0 (36864B)
//      xs[64][288] bf16 @36864 (aliased later by ht[272][64] swizzled)
//      bias_lds[128] f32 @73728
#define LDS_BYTES (36864 + 36864 + 512)

__global__ __launch_bounds__(256, 2)
void fused_kernel(const float* __restrict__ x,
                  const float* __restrict__ bias,
                  const float* __restrict__ conv_b,
                  const unsigned short* __restrict__ ktf,
                  const unsigned short* __restrict__ wf,
                  float* __restrict__ out)
{
    __shared__ char lds[LDS_BYTES];
    float* bias_lds = (float*)(lds + 73728);

    const int tid = threadIdx.x;
    const int blk = blockIdx.x;               // 1024 = b*64 + f
    const int b = blk >> 6, f = blk & 63;
    const int t0 = f << 8;
    const int ln = tid & 63, wv = tid >> 6;
    const int lo = ln & 15, hi = ln >> 4;

    // ---- Phase A1: x -> xs (lrelu, bf16), [ci][p], p = t - (t0-12), 288 cols
    {
        const float* xb = x + (size_t)b*64*16384;
        for (int i4 = tid; i4 < 4608; i4 += TB) {       // 64 ci * 72 float4
            int ci = i4 / 72, pq = i4 % 72;
            int t = t0 - 12 + pq*4;
            float4 v;
            if (t >= 0 && t + 3 < 16384) {
                v = *(const float4*)(xb + ci*16384 + t);
            } else {
                float* pv = (float*)&v;
                #pragma unroll
                for (int e = 0; e < 4; ++e) {
                    int te = t + e;
                    pv[e] = (te >= 0 && te < 16384) ? xb[ci*16384 + te] : 0.f;
                }
            }
            unsigned int w0 = f2bf(lrelu(v.x)) | (f2bf(lrelu(v.y)) << 16);
            unsigned int w1 = f2bf(lrelu(v.z)) | (f2bf(lrelu(v.w)) << 16);
            unsigned int* d = (unsigned int*)(lds + 36864 + ci*576 + pq*8);
            d[0] = w0; d[1] = w1;
        }
        if (tid < 128) bias_lds[tid] = bias[(size_t)b*8192 + tid*64 + f];
    }
    __syncthreads();

    // ---- Phase A2: xs -> xt[p][ci], XOR-swizzled rows
    for (int cc = 0; cc < 2; ++cc) {
        int ci0 = wv*8 + cc*32;
        for (int pp = 0; pp < 5; ++pp) {
            int p = ln + pp*64;
            if (p < 288) {
                ushort8 vv;
                #pragma unroll
                for (int j = 0; j < 8; ++j)
                    vv[j] = *(const unsigned short*)(lds + 36864 + (ci0 + j)*576 + p*2);
                int addr = (p*128 + ci0*2) ^ ((p & 7) << 4);
                *(ushort8*)(lds + addr) = vv;
            }
        }
    }
    __syncthreads();

    // ---- Phase B: dilated conv via MFMA; wave = oc-tile; writes ht[p+8][co]
    {
        short8 aw[6];
        #pragma unroll
        for (int kk = 0; kk < 6; ++kk)
            aw[kk] = *(const short8*)(wf + (size_t)((wv*6 + kk)*64 + ln)*8);
        float4 cb4 = *(const float4*)(conv_b + wv*16 + hi*4);

        for (int nt = 0; nt < 17; ++nt) {                // p = nt*16 + lo - 8
            short8 bq[6];
            #pragma unroll
            for (int kk = 0; kk < 6; ++kk) {
                int row = nt*16 + lo + 3*(kk >> 1) + 1;  // x pos p+3k-3, +12 offset
                int cib = (kk & 1)*32 + hi*8;
                int addr = (row*128 + cib*2) ^ ((row & 7) << 4);
                bq[kk] = *(const short8*)(lds + addr);
            }
            f32x4 acc = {0.f, 0.f, 0.f, 0.f};
            #pragma unroll
            for (int kk = 0; kk < 6; ++kk)
                acc = __builtin_amdgcn_mfma_f32_16x16x32_bf16(aw[kk], bq[kk], acc, 0, 0, 0);

            int pos = t0 + nt*16 + lo - 8;
            bool valid = (unsigned)pos < 16384u;         // h := 0 outside sequence
            unsigned int h0 = valid ? f2bf(lrelu(acc[0] + cb4.x)) : 0u;
            unsigned int h1 = valid ? f2bf(lrelu(acc[1] + cb4.y)) : 0u;
            unsigned int h2 = valid ? f2bf(lrelu(acc[2] + cb4.z)) : 0u;
            unsigned int h3 = valid ? f2bf(lrelu(acc[3] + cb4.w)) : 0u;

            int htrow = nt*16 + lo;
            int addr = 36864 + ((htrow*128 + (wv*16 + hi*4)*2) ^ ((htrow & 7) << 4));
            unsigned int* d = (unsigned int*)(lds + addr);
            d[0] = h0 | (h1 << 16);
            d[1] = h2 | (h3 << 16);
        }
    }
    __syncthreads();

    // ---- Phase C: LVC via MFMA; wave holds oc-tiles {wv, wv+4} (GLU partners)
    {
        const unsigned short* kpage = ktf + (size_t)blk*24576;
        short8 am0[6], am1[6];
        #pragma unroll
        for (int kk = 0; kk < 6; ++kk) {
            am0[kk] = *(const short8*)(kpage + (size_t)(((wv    )*6 + kk)*64 + ln)*8);
            am1[kk] = *(const short8*)(kpage + (size_t)(((wv + 4)*6 + kk)*64 + ln)*8);
        }
        const float* xres = x   + (size_t)b*64*16384;
        float*       outb = out + (size_t)b*64*16384;

        for (int nt = 0; nt < 16; ++nt) {
            int s = nt*16 + lo;
            short8 bq[6];
            #pragma unroll
            for (int kk = 0; kk < 6; ++kk) {
                int row = s + (kk >> 1) + 7;             // h pos s+k-1, +8 offset
                int cib = (kk & 1)*32 + hi*8;
                int addr = 36864 + ((row*128 + cib*2) ^ ((row & 7) << 4));
                bq[kk] = *(const short8*)(lds + addr);
            }
            f32x4 a0 = {0.f,0.f,0.f,0.f}, a1 = {0.f,0.f,0.f,0.f};
            #pragma unroll
            for (int kk = 0; kk < 6; ++kk) {
                a0 = __builtin_amdgcn_mfma_f32_16x16x32_bf16(am0[kk], bq[kk], a0, 0, 0, 0);
                a1 = __builtin_amdgcn_mfma_f32_16x16x32_bf16(am1[kk], bq[kk], a1, 0, 0, 0);
            }
            int t = t0 + s;
            #pragma unroll
            for (int r = 0; r < 4; ++r) {
                int c = wv*16 + hi*4 + r;
                float g = glu_gate(a0[r] + bias_lds[c], a1[r] + bias_lds[c + 64]);
                size_t idx = (size_t)c*16384 + t;
                outb[idx] = xres[idx] + g;
            }
        }
    }
}

extern "C" void kernel_launch(void* const* d_in, const int* in_sizes, int n_in,
                              void* d_out, int out_size, void* d_ws, size_t ws_size,
                              hipStream_t stream)
{
    const float* x      = (const float*)d_in[0];
    const float* kern   = (const float*)d_in[1];
    const float* bias   = (const float*)d_in[2];
    const float* conv_w = (const float*)d_in[3];
    float* out = (float*)d_out;

    if (ws_size < WS_NEED) return;   // harness provides >=100MB (verified R0)

    unsigned short* ktf = (unsigned short*)d_ws;
    unsigned short* wf  = (unsigned short*)((char*)d_ws + KTF_BYTES);

    ktf_transpose<<<dim3(1536), dim3(TB), 0, stream>>>(kern, ktf);
    wf_prep      <<<dim3(6),    dim3(TB), 0, stream>>>((const float*)d_in[3], wf);
    fused_kernel <<<dim3(1024), dim3(TB), 0, stream>>>(x, bias,
                                                       (const float*)d_in[4],
                                                       ktf, wf, out);
    (void)conv_w; (void)in_sizes; (void)n_in; (void)out_size;
}

// Round 4
// 115.493 us; speedup vs baseline: 3.4011x; 1.1607x over previous
//
#include <hip/hip_runtime.h>
#include <hip/hip_bf16.h>

#define TB 256

typedef __attribute__((ext_vector_type(8))) short short8;
typedef __attribute__((ext_vector_type(4))) unsigned int uint4v;
typedef __attribute__((ext_vector_type(4))) float f32x4;

// Problem constants: B=16, C=64, L=16384, HOP=256, KS=3, DIL=3, KL=64
// ws: ktf u32[1024 pages][12288]  (A-frag j-pairs)   = 50,331,648 B
//     wf  u32[6144]               (conv A-frags)     = 24,576 B
#define KTF_BYTES 50331648ull
#define WS_NEED   (KTF_BYTES + 24576ull)

static __device__ __forceinline__ float lrelu(float v){ return v > 0.f ? v : 0.2f*v; }

static __device__ __forceinline__ unsigned int pack2(float lo, float hi){
    __hip_bfloat162 h = __float22bfloat162_rn(float2{lo, hi});
    unsigned int r;
    __builtin_memcpy(&r, &h, 4);
    return r;
}

static __device__ __forceinline__ float glu_gate(float a, float t){
    float sg = 1.0f / (1.0f + __expf(-a));
    float e  = __expf(-2.0f * t);
    float th = 2.0f / (1.0f + e) - 1.0f;
    return sg * th;
}

// ---------------------------------------------------------------------------
// A-frag pair layout: u32 #(kk,jp,mt,ln) = bf16{A[m][r], A[m][r+1]}
//   m = mt*16 + (ln&15);  r = kk*32 + (ln>>4)*8 + 2*jp;  (k = kk>>1, ci = (kk&1)*32 + r&31-part)
// ktf page (b,f): idx = ((kk*4+jp)*8 + mt)*64 + ln   (mt 0..7)
// wf           : idx = ((kk*4+jp)*4 + mt)*64 + ln   (mt 0..3)

// kern[b][ci][oc][k][f] -> ktf. block = (b, ci2 in [0,32), k); ci pair {2ci2, 2ci2+1}
__global__ __launch_bounds__(256, 4)
void ktf_transpose(const float* __restrict__ kern, unsigned int* __restrict__ ktf)
{
    __shared__ unsigned int tl32[128 * 65];            // [oc][f pad65], 33280 B
    const int tid = threadIdx.x;
    const int blk = blockIdx.x;                        // 1536 = b*96 + ci2*3 + k
    const int k   = blk % 3;
    const int ci2 = (blk / 3) % 32;
    const int b   = blk / 96;
    const int kk  = k*2 + (ci2 >> 4);
    const int hi  = (ci2 >> 2) & 3;
    const int jp  = ci2 & 3;

    const float* src0 = kern + (size_t)b*1572864 + (size_t)ci2*49152 + k*64;
    #pragma unroll
    for (int it = 0; it < 8; ++it) {
        int p = tid + it*TB;                           // 2048 = 128 oc * 16 fq
        int oc = p >> 4, fq = p & 15;
        const float* s = src0 + oc*192 + fq*4;
        float4 v0 = *(const float4*)(s);               // ci even
        float4 v1 = *(const float4*)(s + 24576);       // ci odd
        unsigned int* d = tl32 + oc*65 + fq*4;
        d[0] = pack2(v0.x, v1.x);
        d[1] = pack2(v0.y, v1.y);
        d[2] = pack2(v0.z, v1.z);
        d[3] = pack2(v0.w, v1.w);
    }
    __syncthreads();

    const int l = tid & 63, wv = tid >> 6;
    const int mt = l >> 3, lo2 = (2*l) & 15;
    const size_t obase = (size_t)((kk*4 + jp)*8 + mt)*64 + hi*16 + lo2;
    #pragma unroll
    for (int fi = 0; fi < 16; ++fi) {
        int f = wv*16 + fi;
        uint2 v;
        v.x = tl32[(2*l    )*65 + f];
        v.y = tl32[(2*l + 1)*65 + f];
        *(uint2*)(ktf + (size_t)(b*64 + f)*12288 + obase) = v;
    }
}

// conv_w[co][ci][k] -> wf
__global__ __launch_bounds__(256, 4)
void wf_prep(const float* __restrict__ conv_w, unsigned int* __restrict__ wf)
{
    int u = blockIdx.x*TB + threadIdx.x;               // 6144
    int ln = u & 63, mt = (u >> 6) & 3, jp = (u >> 8) & 3, kk = u >> 10;
    int lo = ln & 15, hi = ln >> 4;
    int m  = mt*16 + lo;
    int k  = kk >> 1, ci = (kk & 1)*32 + hi*8 + jp*2;
    float a0 = conv_w[m*192 + ci*3 + k];
    float a1 = conv_w[m*192 + (ci + 1)*3 + k];
    wf[u] = pack2(a0, a1);
}

// ---------------------------------------------------------------------------
// LDS: xt[288][64ci] bf16 swizzled @0 (36864B)
//      xs[64][288] bf16 @36864 (aliased later by ht[272][64] swizzled)
//      bias_lds[128] f32 @73728
#define LDS_BYTES (36864 + 36864 + 512)

__global__ __launch_bounds__(256, 2)
void fused_kernel(const float* __restrict__ x,
                  const float* __restrict__ bias,
                  const float* __restrict__ conv_b,
                  const unsigned int* __restrict__ ktf,
                  const unsigned int* __restrict__ wf,
                  float* __restrict__ out)
{
    __shared__ char lds[LDS_BYTES];
    float* bias_lds = (float*)(lds + 73728);

    const int tid = threadIdx.x;
    const int blk = blockIdx.x;                        // 1024 = b*64 + f
    const int b = blk >> 6, f = blk & 63;
    const int t0 = f << 8;
    const int ln = tid & 63, wv = tid >> 6;
    const int lo = ln & 15, hi = ln >> 4;

    // ---- Prefetch all A-fragments (consumed in phases B/C) ----
    const unsigned int* kp = ktf + (size_t)blk * 12288;
    uint4v am0[6], am1[6], aw[6];
    #pragma unroll
    for (int kk = 0; kk < 6; ++kk) {
        int b0 = kk*2048 + wv*64 + ln;                 // jp stride 512, mt(wv) stride 64
        am0[kk].x = kp[b0      ]; am0[kk].y = kp[b0 +  512];
        am0[kk].z = kp[b0 + 1024]; am0[kk].w = kp[b0 + 1536];
        int b1 = b0 + 256;                             // mt = wv + 4
        am1[kk].x = kp[b1      ]; am1[kk].y = kp[b1 +  512];
        am1[kk].z = kp[b1 + 1024]; am1[kk].w = kp[b1 + 1536];
        int w0 = kk*1024 + wv*64 + ln;                 // jp stride 256
        aw[kk].x = wf[w0      ]; aw[kk].y = wf[w0 + 256];
        aw[kk].z = wf[w0 + 512]; aw[kk].w = wf[w0 + 768];
    }

    // ---- Phase A1: x -> xs (lrelu, bf16), [ci][p], p = t - (t0-12), 288 cols ----
    {
        const float* xb = x + (size_t)b*64*16384;
        const bool interior = (f > 0) & (f < 63);
        #pragma unroll 1
        for (int it = 0; it < 18; ++it) {
            int i4 = tid + it*TB;                      // 4608 = 64 ci * 72 f4
            int ci = i4 / 72, pq = i4 % 72;
            int t = t0 - 12 + pq*4;
            float4 v;
            if (interior) {
                v = *(const float4*)(xb + ci*16384 + t);
            } else {
                float* pv = (float*)&v;
                #pragma unroll
                for (int e = 0; e < 4; ++e) {
                    int te = t + e;
                    pv[e] = ((unsigned)te < 16384u) ? xb[ci*16384 + te] : 0.f;
                }
            }
            uint2 w;
            w.x = pack2(lrelu(v.x), lrelu(v.y));
            w.y = pack2(lrelu(v.z), lrelu(v.w));
            *(uint2*)(lds + 36864 + ci*576 + pq*8) = w;
        }
        if (tid < 128) bias_lds[tid] = bias[(size_t)b*8192 + tid*64 + f];
    }
    __syncthreads();

    // ---- Phase A2: xs -> xt[p][ci], XOR-swizzled rows ----
    #pragma unroll
    for (int cc = 0; cc < 2; ++cc) {
        int ci0 = wv*8 + cc*32;
        #pragma unroll
        for (int pp = 0; pp < 5; ++pp) {
            int p = ln + pp*64;
            if (p < 288) {
                short8 vv;
                #pragma unroll
                for (int j = 0; j < 8; ++j)
                    vv[j] = *(const short*)(lds + 36864 + (ci0 + j)*576 + p*2);
                int addr = (p*128 + ci0*2) ^ ((p & 7) << 4);
                *(short8*)(lds + addr) = vv;
            }
        }
    }
    __syncthreads();

    // ---- Phase B: dilated conv via MFMA; writes ht[pos-(t0-8)][co] ----
    {
        float4 cb4 = *(const float4*)(conv_b + wv*16 + hi*4);
        #pragma unroll 1
        for (int nt = 0; nt < 17; ++nt) {
            short8 bq[6];
            #pragma unroll
            for (int kk = 0; kk < 6; ++kk) {
                int row = nt*16 + lo + 3*(kk >> 1) + 1;
                int cib = (kk & 1)*32 + hi*8;
                int addr = (row*128 + cib*2) ^ ((row & 7) << 4);
                bq[kk] = *(const short8*)(lds + addr);
            }
            f32x4 acc = {0.f, 0.f, 0.f, 0.f};
            #pragma unroll
            for (int kk = 0; kk < 6; ++kk)
                acc = __builtin_amdgcn_mfma_f32_16x16x32_bf16(
                        __builtin_bit_cast(short8, aw[kk]), bq[kk], acc, 0, 0, 0);

            int pos = t0 + nt*16 + lo - 8;
            bool valid = (unsigned)pos < 16384u;
            unsigned int h01 = valid ? pack2(lrelu(acc[0] + cb4.x), lrelu(acc[1] + cb4.y)) : 0u;
            unsigned int h23 = valid ? pack2(lrelu(acc[2] + cb4.z), lrelu(acc[3] + cb4.w)) : 0u;

            int htrow = nt*16 + lo;
            int addr = 36864 + ((htrow*128 + (wv*16 + hi*4)*2) ^ ((htrow & 7) << 4));
            unsigned int* d = (unsigned int*)(lds + addr);
            d[0] = h01; d[1] = h23;
        }
    }
    __syncthreads();

    // ---- Phase C: LVC via MFMA; wave holds oc-tiles {wv, wv+4} (GLU partners) ----
    {
        float ba[4], bb[4];
        size_t rowbase[4];
        #pragma unroll
        for (int r = 0; r < 4; ++r) {
            int c = wv*16 + hi*4 + r;
            ba[r] = bias_lds[c];
            bb[r] = bias_lds[c + 64];
            rowbase[r] = (size_t)(b*64 + c)*16384 + t0 + lo;
        }

        #pragma unroll 1
        for (int nt = 0; nt < 16; ++nt) {
            int s = nt*16 + lo;
            short8 bq[6];
            #pragma unroll
            for (int kk = 0; kk < 6; ++kk) {
                int row = s + (kk >> 1) + 7;
                int cib = (kk & 1)*32 + hi*8;
                int addr = 36864 + ((row*128 + cib*2) ^ ((row & 7) << 4));
                bq[kk] = *(const short8*)(lds + addr);
            }
            f32x4 a0 = {0.f,0.f,0.f,0.f}, a1 = {0.f,0.f,0.f,0.f};
            #pragma unroll
            for (int kk = 0; kk < 6; ++kk) {
                a0 = __builtin_amdgcn_mfma_f32_16x16x32_bf16(
                        __builtin_bit_cast(short8, am0[kk]), bq[kk], a0, 0, 0, 0);
                a1 = __builtin_amdgcn_mfma_f32_16x16x32_bf16(
                        __builtin_bit_cast(short8, am1[kk]), bq[kk], a1, 0, 0, 0);
            }
            #pragma unroll
            for (int r = 0; r < 4; ++r) {
                float g = glu_gate(a0[r] + ba[r], a1[r] + bb[r]);
                size_t idx = rowbase[r] + nt*16;
                out[idx] = x[idx] + g;
            }
        }
    }
}

extern "C" void kernel_launch(void* const* d_in, const int* in_sizes, int n_in,
                              void* d_out, int out_size, void* d_ws, size_t ws_size,
                              hipStream_t stream)
{
    const float* x      = (const float*)d_in[0];
    const float* kern   = (const float*)d_in[1];
    const float* bias   = (const float*)d_in[2];
    const float* conv_b = (const float*)d_in[4];
    float* out = (float*)d_out;

    if (ws_size < WS_NEED) return;   // harness provides >=100MB (verified R0)

    unsigned int* ktf = (unsigned int*)d_ws;
    unsigned int* wf  = (unsigned int*)((char*)d_ws + KTF_BYTES);

    wf_prep      <<<dim3(24),   dim3(TB), 0, stream>>>((const float*)d_in[3], wf);
    ktf_transpose<<<dim3(1536), dim3(TB), 0, stream>>>(kern, ktf);
    fused_kernel <<<dim3(1024), dim3(TB), 0, stream>>>(x, bias, conv_b, ktf, wf, out);
    (void)in_sizes; (void)n_in; (void)out_size;
}

// Round 5
// 98.051 us; speedup vs baseline: 4.0061x; 1.1779x over previous
//
#include <hip/hip_runtime.h>
#include <hip/hip_bf16.h>

#define TB 256

typedef __attribute__((ext_vector_type(8))) short short8;
typedef __attribute__((ext_vector_type(4))) unsigned int uint4v;
typedef __attribute__((ext_vector_type(4))) float f32x4;

// Problem constants: B=16, C=64, L=16384, HOP=256, KS=3, DIL=3, KL=64
// ws: ktf u32[1024 pages][12288]  (A-frag j-pairs)   = 50,331,648 B
//     wf  u32[6144]               (conv A-frags)     = 24,576 B
#define KTF_BYTES 50331648ull
#define WS_NEED   (KTF_BYTES + 24576ull)

static __device__ __forceinline__ float lrelu(float v){ return v > 0.f ? v : 0.2f*v; }

static __device__ __forceinline__ unsigned int pack2(float lo, float hi){
    __hip_bfloat162 h = __float22bfloat162_rn(float2{lo, hi});
    unsigned int r;
    __builtin_memcpy(&r, &h, 4);
    return r;
}

static __device__ __forceinline__ float bf2f(unsigned short u){
    return __uint_as_float(((unsigned int)u) << 16);
}

static __device__ __forceinline__ float glu_gate(float a, float t){
    float sg = 1.0f / (1.0f + __expf(-a));
    float e  = __expf(-2.0f * t);
    float th = 2.0f / (1.0f + e) - 1.0f;
    return sg * th;
}

// ---------------------------------------------------------------------------
// A-frag pair layout: u32 #(kk,jp,mt,ln) = bf16{A[m][r], A[m][r+1]}
//   m = mt*16 + (ln&15);  r = kk*32 + (ln>>4)*8 + 2*jp
// ktf page (b,f): idx = ((kk*4+jp)*8 + mt)*64 + ln   (mt 0..7)
// wf           : idx = ((kk*4+jp)*4 + mt)*64 + ln   (mt 0..3)

__global__ __launch_bounds__(256, 4)
void ktf_transpose(const float* __restrict__ kern, unsigned int* __restrict__ ktf)
{
    __shared__ unsigned int tl32[128 * 65];            // [oc][f pad65], 33280 B
    const int tid = threadIdx.x;
    const int blk = blockIdx.x;                        // 1536 = b*96 + ci2*3 + k
    const int k   = blk % 3;
    const int ci2 = (blk / 3) % 32;
    const int b   = blk / 96;
    const int kk  = k*2 + (ci2 >> 4);
    const int hi  = (ci2 >> 2) & 3;
    const int jp  = ci2 & 3;

    const float* src0 = kern + (size_t)b*1572864 + (size_t)ci2*49152 + k*64;
    #pragma unroll
    for (int it = 0; it < 8; ++it) {
        int p = tid + it*TB;                           // 2048 = 128 oc * 16 fq
        int oc = p >> 4, fq = p & 15;
        const float* s = src0 + oc*192 + fq*4;
        float4 v0 = *(const float4*)(s);               // ci even
        float4 v1 = *(const float4*)(s + 24576);       // ci odd
        unsigned int* d = tl32 + oc*65 + fq*4;
        d[0] = pack2(v0.x, v1.x);
        d[1] = pack2(v0.y, v1.y);
        d[2] = pack2(v0.z, v1.z);
        d[3] = pack2(v0.w, v1.w);
    }
    __syncthreads();

    const int l = tid & 63, wv = tid >> 6;
    const int mt = l >> 3, lo2 = (2*l) & 15;
    const size_t obase = (size_t)((kk*4 + jp)*8 + mt)*64 + hi*16 + lo2;
    #pragma unroll
    for (int fi = 0; fi < 16; ++fi) {
        int f = wv*16 + fi;
        uint2 v;
        v.x = tl32[(2*l    )*65 + f];
        v.y = tl32[(2*l + 1)*65 + f];
        *(uint2*)(ktf + (size_t)(b*64 + f)*12288 + obase) = v;
    }
}

// conv_w[co][ci][k] -> wf
__global__ __launch_bounds__(256, 4)
void wf_prep(const float* __restrict__ conv_w, unsigned int* __restrict__ wf)
{
    int u = blockIdx.x*TB + threadIdx.x;               // 6144
    int ln = u & 63, mt = (u >> 6) & 3, jp = (u >> 8) & 3, kk = u >> 10;
    int lo = ln & 15, hi = ln >> 4;
    int m  = mt*16 + lo;
    int k  = kk >> 1, ci = (kk & 1)*32 + hi*8 + jp*2;
    float a0 = conv_w[m*192 + ci*3 + k];
    float a1 = conv_w[m*192 + (ci + 1)*3 + k];
    wf[u] = pack2(a0, a1);
}

// ---------------------------------------------------------------------------
// LDS: xt[288][64ci] bf16 swizzled @0 (36864B)
//      xs[64][288] bf16 RAW x @36864 (aliased later by ht[272][64] swizzled)
//      bias_lds[128] f32 @73728
#define LDS_BYTES (36864 + 36864 + 512)

__global__ __launch_bounds__(256, 2)
void fused_kernel(const float* __restrict__ x,
                  const float* __restrict__ bias,
                  const float* __restrict__ conv_b,
                  const unsigned int* __restrict__ ktf,
                  const unsigned int* __restrict__ wf,
                  float* __restrict__ out)
{
    __shared__ char lds[LDS_BYTES];
    float* bias_lds = (float*)(lds + 73728);

    const int tid = threadIdx.x;
    const int blk = blockIdx.x;                        // 1024 = b*64 + f
    const int b = blk >> 6, f = blk & 63;
    const int t0 = f << 8;
    const int ln = tid & 63, wv = tid >> 6;
    const int lo = ln & 15, hi = ln >> 4;

    // ---- Phase A1a: issue ALL x-tile loads first (oldest in vmcnt order) ----
    float4 xv[18];
    {
        const float* xb = x + (size_t)b*64*16384;
        if ((f > 0) & (f < 63)) {
            #pragma unroll
            for (int it = 0; it < 18; ++it) {
                int i4 = tid + it*TB;                  // 4608 = 64 ci * 72 f4
                int ci = i4 / 72, pq = i4 % 72;
                xv[it] = *(const float4*)(xb + ci*16384 + t0 - 12 + pq*4);
            }
        } else {
            #pragma unroll
            for (int it = 0; it < 18; ++it) {
                int i4 = tid + it*TB;
                int ci = i4 / 72, pq = i4 % 72;
                int t = t0 - 12 + pq*4;
                float* pv = (float*)&xv[it];
                #pragma unroll
                for (int e = 0; e < 4; ++e) {
                    int te = t + e;
                    pv[e] = ((unsigned)te < 16384u) ? xb[ci*16384 + te] : 0.f;
                }
            }
        }
    }
    __builtin_amdgcn_sched_barrier(0);

    // ---- Issue aw (needed in phase B), then am (needed in phase C) ----
    uint4v aw[6], am0[6], am1[6];
    #pragma unroll
    for (int kk = 0; kk < 6; ++kk) {
        int w0 = kk*1024 + wv*64 + ln;                 // jp stride 256
        aw[kk].x = wf[w0      ]; aw[kk].y = wf[w0 + 256];
        aw[kk].z = wf[w0 + 512]; aw[kk].w = wf[w0 + 768];
    }
    __builtin_amdgcn_sched_barrier(0);
    const unsigned int* kp = ktf + (size_t)blk * 12288;
    #pragma unroll
    for (int kk = 0; kk < 6; ++kk) {
        int b0 = kk*2048 + wv*64 + ln;                 // jp stride 512, mt stride 64
        am0[kk].x = kp[b0      ]; am0[kk].y = kp[b0 +  512];
        am0[kk].z = kp[b0 + 1024]; am0[kk].w = kp[b0 + 1536];
        int b1 = b0 + 256;                             // mt = wv + 4
        am1[kk].x = kp[b1      ]; am1[kk].y = kp[b1 +  512];
        am1[kk].z = kp[b1 + 1024]; am1[kk].w = kp[b1 + 1536];
    }
    __builtin_amdgcn_sched_barrier(0);

    // ---- Phase A1b: convert x -> xs (RAW bf16), [ci][p], p = t-(t0-12) ----
    {
        #pragma unroll
        for (int it = 0; it < 18; ++it) {
            int i4 = tid + it*TB;
            int ci = i4 / 72, pq = i4 % 72;
            uint2 w;
            w.x = pack2(xv[it].x, xv[it].y);
            w.y = pack2(xv[it].z, xv[it].w);
            *(uint2*)(lds + 36864 + ci*576 + pq*8) = w;
        }
        if (tid < 128) bias_lds[tid] = bias[(size_t)b*8192 + tid*64 + f];
    }
    __syncthreads();

    // ---- Phase A2: xs -> xt[p][ci] (lrelu applied here), XOR-swizzled ----
    #pragma unroll
    for (int cc = 0; cc < 2; ++cc) {
        int ci0 = wv*8 + cc*32;
        #pragma unroll
        for (int pp = 0; pp < 5; ++pp) {
            int p = ln + pp*64;
            if (p < 288) {
                unsigned int vv[4];
                #pragma unroll
                for (int jq = 0; jq < 4; ++jq) {
                    unsigned short r0 = *(const unsigned short*)(lds + 36864 + (ci0 + 2*jq    )*576 + p*2);
                    unsigned short r1 = *(const unsigned short*)(lds + 36864 + (ci0 + 2*jq + 1)*576 + p*2);
                    vv[jq] = pack2(lrelu(bf2f(r0)), lrelu(bf2f(r1)));
                }
                int addr = (p*128 + ci0*2) ^ ((p & 7) << 4);
                *(uint4*)(lds + addr) = make_uint4(vv[0], vv[1], vv[2], vv[3]);
            }
        }
    }

    // ---- Snapshot residuals from xs before ht overwrites it ----
    // resid[r*8+np] packs x[c][t0+2np*16+lo] (lo half) and x[c][t0+(2np+1)*16+lo] (hi)
    unsigned int resid[32];
    #pragma unroll
    for (int r = 0; r < 4; ++r) {
        int c = wv*16 + hi*4 + r;
        const char* basep = lds + 36864 + c*576 + (12 + lo)*2;
        #pragma unroll
        for (int np = 0; np < 8; ++np) {
            unsigned short e0 = *(const unsigned short*)(basep + (np*32)*2);
            unsigned short e1 = *(const unsigned short*)(basep + (np*32 + 16)*2);
            resid[r*8 + np] = (unsigned int)e0 | ((unsigned int)e1 << 16);
        }
    }
    __syncthreads();

    // ---- Phase B: dilated conv via MFMA; writes ht[pos-(t0-8)][co] ----
    {
        float4 cb4 = *(const float4*)(conv_b + wv*16 + hi*4);
        #pragma unroll 2
        for (int nt = 0; nt < 17; ++nt) {
            short8 bq[6];
            #pragma unroll
            for (int kk = 0; kk < 6; ++kk) {
                int row = nt*16 + lo + 3*(kk >> 1) + 1;
                int cib = (kk & 1)*32 + hi*8;
                int addr = (row*128 + cib*2) ^ ((row & 7) << 4);
                bq[kk] = *(const short8*)(lds + addr);
            }
            f32x4 acc = {0.f, 0.f, 0.f, 0.f};
            #pragma unroll
            for (int kk = 0; kk < 6; ++kk)
                acc = __builtin_amdgcn_mfma_f32_16x16x32_bf16(
                        __builtin_bit_cast(short8, aw[kk]), bq[kk], acc, 0, 0, 0);

            int pos = t0 + nt*16 + lo - 8;
            bool valid = (unsigned)pos < 16384u;
            unsigned int h01 = valid ? pack2(lrelu(acc[0] + cb4.x), lrelu(acc[1] + cb4.y)) : 0u;
            unsigned int h23 = valid ? pack2(lrelu(acc[2] + cb4.z), lrelu(acc[3] + cb4.w)) : 0u;

            int htrow = nt*16 + lo;
            int addr = 36864 + ((htrow*128 + (wv*16 + hi*4)*2) ^ ((htrow & 7) << 4));
            unsigned int* d = (unsigned int*)(lds + addr);
            d[0] = h01; d[1] = h23;
        }
    }
    __syncthreads();

    // ---- Phase C: LVC via MFMA; wave holds oc-tiles {wv, wv+4} (GLU partners) ----
    {
        float ba[4], bb[4];
        size_t rowbase[4];
        #pragma unroll
        for (int r = 0; r < 4; ++r) {
            int c = wv*16 + hi*4 + r;
            ba[r] = bias_lds[c];
            bb[r] = bias_lds[c + 64];
            rowbase[r] = (size_t)(b*64 + c)*16384 + t0 + lo;
        }

        #pragma unroll
        for (int nt = 0; nt < 16; ++nt) {
            int s = nt*16 + lo;
            short8 bq[6];
            #pragma unroll
            for (int kk = 0; kk < 6; ++kk) {
                int row = s + (kk >> 1) + 7;
                int cib = (kk & 1)*32 + hi*8;
                int addr = 36864 + ((row*128 + cib*2) ^ ((row & 7) << 4));
                bq[kk] = *(const short8*)(lds + addr);
            }
            f32x4 a0 = {0.f,0.f,0.f,0.f}, a1 = {0.f,0.f,0.f,0.f};
            #pragma unroll
            for (int kk = 0; kk < 6; ++kk) {
                a0 = __builtin_amdgcn_mfma_f32_16x16x32_bf16(
                        __builtin_bit_cast(short8, am0[kk]), bq[kk], a0, 0, 0, 0);
                a1 = __builtin_amdgcn_mfma_f32_16x16x32_bf16(
                        __builtin_bit_cast(short8, am1[kk]), bq[kk], a1, 0, 0, 0);
            }
            #pragma unroll
            for (int r = 0; r < 4; ++r) {
                unsigned int pr = resid[r*8 + (nt >> 1)];
                float xr = __uint_as_float((nt & 1) ? (pr & 0xFFFF0000u) : (pr << 16));
                float g = glu_gate(a0[r] + ba[r], a1[r] + bb[r]);
                out[rowbase[r] + nt*16] = xr + g;
            }
        }
    }
}

extern "C" void kernel_launch(void* const* d_in, const int* in_sizes, int n_in,
                              void* d_out, int out_size, void* d_ws, size_t ws_size,
                              hipStream_t stream)
{
    const float* x      = (const float*)d_in[0];
    const float* kern   = (const float*)d_in[1];
    const float* bias   = (const float*)d_in[2];
    const float* conv_b = (const float*)d_in[4];
    float* out = (float*)d_out;

    if (ws_size < WS_NEED) return;   // harness provides >=100MB (verified R0)

    unsigned int* ktf = (unsigned int*)d_ws;
    unsigned int* wf  = (unsigned int*)((char*)d_ws + KTF_BYTES);

    wf_prep      <<<dim3(24),   dim3(TB), 0, stream>>>((const float*)d_in[3], wf);
    ktf_transpose<<<dim3(1536), dim3(TB), 0, stream>>>(kern, ktf);
    fused_kernel <<<dim3(1024), dim3(TB), 0, stream>>>(x, bias, conv_b, ktf, wf, out);
    (void)in_sizes; (void)n_in; (void)out_size;
}

// Round 6
// 90.517 us; speedup vs baseline: 4.3396x; 1.0832x over previous
//
#include <hip/hip_runtime.h>
#include <hip/hip_bf16.h>

#define TB 256

typedef __attribute__((ext_vector_type(8))) short short8;
typedef __attribute__((ext_vector_type(4))) unsigned int uint4v;
typedef __attribute__((ext_vector_type(4))) float f32x4;

// Problem constants: B=16, C=64, L=16384, HOP=256, KS=3, DIL=3, KL=64
// ws: ktf u32[1024 pages][12288]  (A-frag j-pairs)   = 50,331,648 B
//     wf  u32[6144]               (conv A-frags)     = 24,576 B
#define KTF_BYTES 50331648ull
#define WS_NEED   (KTF_BYTES + 24576ull)

static __device__ __forceinline__ float lrelu(float v){ return v > 0.f ? v : 0.2f*v; }

static __device__ __forceinline__ unsigned int pack2(float lo, float hi){
    __hip_bfloat162 h = __float22bfloat162_rn(float2{lo, hi});
    unsigned int r;
    __builtin_memcpy(&r, &h, 4);
    return r;
}

static __device__ __forceinline__ float bf2f(unsigned int u16v){
    return __uint_as_float(u16v << 16);
}

static __device__ __forceinline__ float glu_gate(float a, float t){
    float sg = 1.0f / (1.0f + __expf(-a));
    float e  = __expf(-2.0f * t);
    float th = 2.0f / (1.0f + e) - 1.0f;
    return sg * th;
}

// ---------------------------------------------------------------------------
// A-frag pair layout: u32 #(kk,jp,mt,ln) = bf16{A[m][r], A[m][r+1]}
//   m = mt*16 + (ln&15);  r = kk*32 + (ln>>4)*8 + 2*jp
// ktf page (b,f): idx = ((kk*4+jp)*8 + mt)*64 + ln   (mt 0..7)
// wf           : idx = ((kk*4+jp)*4 + mt)*64 + ln   (mt 0..3)

__global__ __launch_bounds__(256, 4)
void ktf_transpose(const float* __restrict__ kern, unsigned int* __restrict__ ktf)
{
    __shared__ unsigned int tl32[128 * 65];            // [oc][f pad65], 33280 B
    const int tid = threadIdx.x;
    const int blk = blockIdx.x;                        // 1536 = b*96 + ci2*3 + k
    const int k   = blk % 3;
    const int ci2 = (blk / 3) % 32;
    const int b   = blk / 96;
    const int kk  = k*2 + (ci2 >> 4);
    const int hi  = (ci2 >> 2) & 3;
    const int jp  = ci2 & 3;

    const float* src0 = kern + (size_t)b*1572864 + (size_t)ci2*49152 + k*64;
    #pragma unroll
    for (int it = 0; it < 8; ++it) {
        int p = tid + it*TB;                           // 2048 = 128 oc * 16 fq
        int oc = p >> 4, fq = p & 15;
        const float* s = src0 + oc*192 + fq*4;
        float4 v0 = *(const float4*)(s);               // ci even
        float4 v1 = *(const float4*)(s + 24576);       // ci odd
        unsigned int* d = tl32 + oc*65 + fq*4;
        d[0] = pack2(v0.x, v1.x);
        d[1] = pack2(v0.y, v1.y);
        d[2] = pack2(v0.z, v1.z);
        d[3] = pack2(v0.w, v1.w);
    }
    __syncthreads();

    const int l = tid & 63, wv = tid >> 6;
    const int mt = l >> 3, lo2 = (2*l) & 15;
    const size_t obase = (size_t)((kk*4 + jp)*8 + mt)*64 + hi*16 + lo2;
    #pragma unroll
    for (int fi = 0; fi < 16; ++fi) {
        int f = wv*16 + fi;
        uint2 v;
        v.x = tl32[(2*l    )*65 + f];
        v.y = tl32[(2*l + 1)*65 + f];
        *(uint2*)(ktf + (size_t)(b*64 + f)*12288 + obase) = v;
    }
}

// conv_w[co][ci][k] -> wf
__global__ __launch_bounds__(256, 4)
void wf_prep(const float* __restrict__ conv_w, unsigned int* __restrict__ wf)
{
    int u = blockIdx.x*TB + threadIdx.x;               // 6144
    int ln = u & 63, mt = (u >> 6) & 3, jp = (u >> 8) & 3, kk = u >> 10;
    int lo = ln & 15, hi = ln >> 4;
    int m  = mt*16 + lo;
    int k  = kk >> 1, ci = (kk & 1)*32 + hi*8 + jp*2;
    float a0 = conv_w[m*192 + ci*3 + k];
    float a1 = conv_w[m*192 + (ci + 1)*3 + k];
    wf[u] = pack2(a0, a1);
}

// ---------------------------------------------------------------------------
// LDS: xt[288][64ci] bf16 swizzled @0 (36864B)   [lrelu'd x; also resid source]
//      ht[272][64]  bf16 swizzled @36864 (34816B)
//      bias_lds[128] f32 @71680
#define LDS_BYTES (36864 + 34816 + 512)

__global__ __launch_bounds__(512, 4)
void fused_kernel(const float* __restrict__ x,
                  const float* __restrict__ bias,
                  const float* __restrict__ conv_b,
                  const unsigned int* __restrict__ ktf,
                  const unsigned int* __restrict__ wf,
                  float* __restrict__ out)
{
    __shared__ char lds[LDS_BYTES];
    float* bias_lds = (float*)(lds + 71680);

    const int tid = threadIdx.x;
    const int blk = blockIdx.x;                        // 1024 = b*64 + f
    const int b = blk >> 6, f = blk & 63;
    const int t0 = f << 8;
    const int ln = tid & 63, wv = tid >> 6;            // 8 waves
    const int lo = ln & 15, hi = ln >> 4;
    const int mt = wv & 3, nth = wv >> 2;

    // ---- Phase A: transposed load x -> xt (lrelu, bf16, swizzled) ----
    // thread: p = ln + 64*it (time-col), g = wv (ci octet); coalesced 256B/instr
    {
        const int g = wv;
        const float* xb = x + ((size_t)b*64 + g*8) * 16384;
        const bool interior = (f > 0) & (f < 63);
        #pragma unroll
        for (int it = 0; it < 5; ++it) {
            if (it < 4 || ln < 32) {
                int p = ln + it*64;
                int t = t0 - 12 + p;
                float v[8];
                if (interior) {
                    #pragma unroll
                    for (int j = 0; j < 8; ++j) v[j] = xb[j*16384 + t];
                } else {
                    bool ok = (unsigned)t < 16384u;
                    #pragma unroll
                    for (int j = 0; j < 8; ++j) v[j] = ok ? xb[j*16384 + t] : 0.f;
                }
                unsigned int w0 = pack2(lrelu(v[0]), lrelu(v[1]));
                unsigned int w1 = pack2(lrelu(v[2]), lrelu(v[3]));
                unsigned int w2 = pack2(lrelu(v[4]), lrelu(v[5]));
                unsigned int w3 = pack2(lrelu(v[6]), lrelu(v[7]));
                int addr = (p*128 + g*16) ^ ((p & 7) << 4);
                *(uint4*)(lds + addr) = make_uint4(w0, w1, w2, w3);
            }
        }
        if (tid < 128) bias_lds[tid] = bias[(size_t)b*8192 + tid*64 + f];
    }
    __syncthreads();

    // ---- Phase B: dilated conv via MFMA; wave (mt, nth); writes ht ----
    {
        uint4v aw[6];
        #pragma unroll
        for (int kk = 0; kk < 6; ++kk) {
            int w0 = kk*1024 + mt*64 + ln;             // jp stride 256
            aw[kk].x = wf[w0      ]; aw[kk].y = wf[w0 + 256];
            aw[kk].z = wf[w0 + 512]; aw[kk].w = wf[w0 + 768];
        }
        float4 cb4 = *(const float4*)(conv_b + mt*16 + hi*4);
        const int n0  = nth ? 9 : 0;
        const int cnt = nth ? 8 : 9;                   // nt 0..8 | 9..16
        #pragma unroll 1
        for (int i = 0; i < cnt; ++i) {
            int nt = n0 + i;
            short8 bq[6];
            #pragma unroll
            for (int kk = 0; kk < 6; ++kk) {
                int row = nt*16 + lo + 3*(kk >> 1) + 1;
                int cib = (kk & 1)*32 + hi*8;
                int addr = (row*128 + cib*2) ^ ((row & 7) << 4);
                bq[kk] = *(const short8*)(lds + addr);
            }
            f32x4 acc = {0.f, 0.f, 0.f, 0.f};
            __builtin_amdgcn_s_setprio(1);
            #pragma unroll
            for (int kk = 0; kk < 6; ++kk)
                acc = __builtin_amdgcn_mfma_f32_16x16x32_bf16(
                        __builtin_bit_cast(short8, aw[kk]), bq[kk], acc, 0, 0, 0);
            __builtin_amdgcn_s_setprio(0);

            int pos = t0 + nt*16 + lo - 8;
            bool valid = (unsigned)pos < 16384u;
            unsigned int h01 = valid ? pack2(lrelu(acc[0] + cb4.x), lrelu(acc[1] + cb4.y)) : 0u;
            unsigned int h23 = valid ? pack2(lrelu(acc[2] + cb4.z), lrelu(acc[3] + cb4.w)) : 0u;

            int htrow = nt*16 + lo;
            int addr = 36864 + ((htrow*128 + (mt*16 + hi*4)*2) ^ ((htrow & 7) << 4));
            unsigned int* d = (unsigned int*)(lds + addr);
            d[0] = h01; d[1] = h23;
        }
    }
    __syncthreads();

    // ---- Phase C: LVC via MFMA; wave (mt,nth) owns oc-tiles {mt, mt+4} ----
    {
        const unsigned int* kp = ktf + (size_t)blk * 12288;
        uint4v am0[6], am1[6];
        #pragma unroll
        for (int kk = 0; kk < 6; ++kk) {
            int b0 = kk*2048 + mt*64 + ln;             // jp stride 512, mt stride 64
            am0[kk].x = kp[b0      ]; am0[kk].y = kp[b0 +  512];
            am0[kk].z = kp[b0 + 1024]; am0[kk].w = kp[b0 + 1536];
            int b1 = b0 + 256;                         // mt + 4
            am1[kk].x = kp[b1      ]; am1[kk].y = kp[b1 +  512];
            am1[kk].z = kp[b1 + 1024]; am1[kk].w = kp[b1 + 1536];
        }
        float ba[4], bb[4];
        size_t rowbase[4];
        #pragma unroll
        for (int r = 0; r < 4; ++r) {
            int c = mt*16 + hi*4 + r;
            ba[r] = bias_lds[c];
            bb[r] = bias_lds[c + 64];
            rowbase[r] = (size_t)(b*64 + c)*16384 + t0 + lo;
        }

        #pragma unroll 1
        for (int i = 0; i < 8; ++i) {
            int nt = nth*8 + i;
            int s = nt*16 + lo;
            short8 bq[6];
            #pragma unroll
            for (int kk = 0; kk < 6; ++kk) {
                int row = s + (kk >> 1) + 7;
                int cib = (kk & 1)*32 + hi*8;
                int addr = 36864 + ((row*128 + cib*2) ^ ((row & 7) << 4));
                bq[kk] = *(const short8*)(lds + addr);
            }
            // residual from live xt tile (lrelu is invertible)
            int p = s + 12;
            int raddr = (p*128 + (mt*16 + hi*4)*2) ^ ((p & 7) << 4);
            uint2 rv = *(const uint2*)(lds + raddr);

            f32x4 a0 = {0.f,0.f,0.f,0.f}, a1 = {0.f,0.f,0.f,0.f};
            __builtin_amdgcn_s_setprio(1);
            #pragma unroll
            for (int kk = 0; kk < 6; ++kk) {
                a0 = __builtin_amdgcn_mfma_f32_16x16x32_bf16(
                        __builtin_bit_cast(short8, am0[kk]), bq[kk], a0, 0, 0, 0);
                a1 = __builtin_amdgcn_mfma_f32_16x16x32_bf16(
                        __builtin_bit_cast(short8, am1[kk]), bq[kk], a1, 0, 0, 0);
            }
            __builtin_amdgcn_s_setprio(0);

            #pragma unroll
            for (int r = 0; r < 4; ++r) {
                unsigned int u = (r < 2 ? rv.x : rv.y) >> ((r & 1) * 16);
                float hv = bf2f(u & 0xFFFFu);
                float xr = hv > 0.f ? hv : 5.0f * hv;  // inverse lrelu
                float g  = glu_gate(a0[r] + ba[r], a1[r] + bb[r]);
                out[rowbase[r] + nt*16] = xr + g;
            }
        }
    }
}

extern "C" void kernel_launch(void* const* d_in, const int* in_sizes, int n_in,
                              void* d_out, int out_size, void* d_ws, size_t ws_size,
                              hipStream_t stream)
{
    const float* x      = (const float*)d_in[0];
    const float* kern   = (const float*)d_in[1];
    const float* bias   = (const float*)d_in[2];
    const float* conv_b = (const float*)d_in[4];
    float* out = (float*)d_out;

    if (ws_size < WS_NEED) return;   // harness provides >=100MB (verified R0)

    unsigned int* ktf = (unsigned int*)d_ws;
    unsigned int* wf  = (unsigned int*)((char*)d_ws + KTF_BYTES);

    wf_prep      <<<dim3(24),   dim3(TB), 0, stream>>>((const float*)d_in[3], wf);
    ktf_transpose<<<dim3(1536), dim3(TB), 0, stream>>>(kern, ktf);
    fused_kernel <<<dim3(1024), dim3(512), 0, stream>>>(x, bias, conv_b, ktf, wf, out);
    (void)in_sizes; (void)n_in; (void)out_size;
}

// Round 7
// 84.295 us; speedup vs baseline: 4.6599x; 1.0738x over previous
//
#include <hip/hip_runtime.h>
#include <hip/hip_bf16.h>

#define TB 256

typedef __attribute__((ext_vector_type(8))) short short8;
typedef __attribute__((ext_vector_type(4))) unsigned int uint4v;
typedef __attribute__((ext_vector_type(4))) float f32x4;

// Problem constants: B=16, C=64, L=16384, HOP=256, KS=3, DIL=3, KL=64
// ws: ktf u32[1024 pages][12288]  (A-frag j-pairs)   = 50,331,648 B
//     wf  u32[6144]               (conv A-frags)     = 24,576 B
#define KTF_BYTES 50331648ull
#define WS_NEED   (KTF_BYTES + 24576ull)

static __device__ __forceinline__ float lrelu(float v){ return v > 0.f ? v : 0.2f*v; }

static __device__ __forceinline__ unsigned int pack2(float lo, float hi){
    __hip_bfloat162 h = __float22bfloat162_rn(float2{lo, hi});
    unsigned int r;
    __builtin_memcpy(&r, &h, 4);
    return r;
}

static __device__ __forceinline__ float bf2f(unsigned int u16v){
    return __uint_as_float(u16v << 16);
}

// sigmoid(a)*tanh(t) = (v-1) / ((1+u)(v+1)),  u=e^-a, v=e^{2t}
// 2 exp + 1 rcp (vs 2 exp + 2 full divisions before)
static __device__ __forceinline__ float glu_gate(float a, float t){
    t = fminf(fmaxf(t, -10.f), 10.f);          // tanh saturated; avoids v=inf
    float u = __expf(-a);
    float v = __expf(2.0f * t);
    float den = (1.0f + u) * (v + 1.0f);
    return (v - 1.0f) * __builtin_amdgcn_rcpf(den);
}

// ---------------------------------------------------------------------------
// A-frag pair layout: u32 #(kk,jp,mt,ln) = bf16{A[m][r], A[m][r+1]}
//   m = mt*16 + (ln&15);  r = kk*32 + (ln>>4)*8 + 2*jp
// ktf page (b,f): idx = ((kk*4+jp)*8 + mt)*64 + ln   (mt 0..7)
// wf           : idx = ((kk*4+jp)*4 + mt)*64 + ln   (mt 0..3)

__global__ __launch_bounds__(256, 4)
void ktf_transpose(const float* __restrict__ kern, unsigned int* __restrict__ ktf)
{
    __shared__ unsigned int tl32[128 * 65];            // [oc][f pad65], 33280 B
    const int tid = threadIdx.x;
    const int blk = blockIdx.x;                        // 1536 = b*96 + ci2*3 + k
    const int k   = blk % 3;
    const int ci2 = (blk / 3) % 32;
    const int b   = blk / 96;
    const int kk  = k*2 + (ci2 >> 4);
    const int hi  = (ci2 >> 2) & 3;
    const int jp  = ci2 & 3;

    const float* src0 = kern + (size_t)b*1572864 + (size_t)ci2*49152 + k*64;
    #pragma unroll
    for (int it = 0; it < 8; ++it) {
        int p = tid + it*TB;                           // 2048 = 128 oc * 16 fq
        int oc = p >> 4, fq = p & 15;
        const float* s = src0 + oc*192 + fq*4;
        float4 v0 = *(const float4*)(s);               // ci even
        float4 v1 = *(const float4*)(s + 24576);       // ci odd
        unsigned int* d = tl32 + oc*65 + fq*4;
        d[0] = pack2(v0.x, v1.x);
        d[1] = pack2(v0.y, v1.y);
        d[2] = pack2(v0.z, v1.z);
        d[3] = pack2(v0.w, v1.w);
    }
    __syncthreads();

    const int l = tid & 63, wv = tid >> 6;
    const int mt = l >> 3, lo2 = (2*l) & 15;
    const size_t obase = (size_t)((kk*4 + jp)*8 + mt)*64 + hi*16 + lo2;
    #pragma unroll
    for (int fi = 0; fi < 16; ++fi) {
        int f = wv*16 + fi;
        uint2 v;
        v.x = tl32[(2*l    )*65 + f];
        v.y = tl32[(2*l + 1)*65 + f];
        *(uint2*)(ktf + (size_t)(b*64 + f)*12288 + obase) = v;
    }
}

// conv_w[co][ci][k] -> wf
__global__ __launch_bounds__(256, 4)
void wf_prep(const float* __restrict__ conv_w, unsigned int* __restrict__ wf)
{
    int u = blockIdx.x*TB + threadIdx.x;               // 6144
    int ln = u & 63, mt = (u >> 6) & 3, jp = (u >> 8) & 3, kk = u >> 10;
    int lo = ln & 15, hi = ln >> 4;
    int m  = mt*16 + lo;
    int k  = kk >> 1, ci = (kk & 1)*32 + hi*8 + jp*2;
    float a0 = conv_w[m*192 + ci*3 + k];
    float a1 = conv_w[m*192 + (ci + 1)*3 + k];
    wf[u] = pack2(a0, a1);
}

// ---------------------------------------------------------------------------
// LDS: xt[288][64ci] bf16 swizzled @0 (36864B)   [lrelu'd x; also resid source]
//      ht[272][64]  bf16 swizzled @36864 (34816B)
//      bias_lds[128] f32 @71680
#define LDS_BYTES (36864 + 34816 + 512)

__global__ __launch_bounds__(512, 4)
void fused_kernel(const float* __restrict__ x,
                  const float* __restrict__ bias,
                  const float* __restrict__ conv_b,
                  const unsigned int* __restrict__ ktf,
                  const unsigned int* __restrict__ wf,
                  float* __restrict__ out)
{
    __shared__ char lds[LDS_BYTES];
    float* bias_lds = (float*)(lds + 71680);

    const int tid = threadIdx.x;
    const int blk = blockIdx.x;                        // 1024 = b*64 + f
    const int b = blk >> 6, f = blk & 63;
    const int t0 = f << 8;
    const int ln = tid & 63, wv = tid >> 6;            // 8 waves
    const int lo = ln & 15, hi = ln >> 4;
    const int mt = wv & 3, nth = wv >> 2;

    // ---- A1: issue x-tile loads FIRST (oldest in vmcnt order) ----
    // wave g=wv owns ci octet; lane covers p = 2*ln (+128*it): float2, 512B/wave
    const int g = wv;
    const float* xb = x + ((size_t)b*64 + g*8) * 16384;
    float2 xv[24];
    {
        const bool interior = (f > 0) & (f < 63);
        if (interior) {
            #pragma unroll
            for (int it = 0; it < 3; ++it) {
                if (it < 2 || ln < 16) {
                    int t = t0 - 12 + 2*ln + it*128;
                    #pragma unroll
                    for (int j = 0; j < 8; ++j)
                        xv[it*8 + j] = *(const float2*)(xb + j*16384 + t);
                }
            }
        } else {
            #pragma unroll
            for (int it = 0; it < 3; ++it) {
                if (it < 2 || ln < 16) {
                    int t = t0 - 12 + 2*ln + it*128;
                    #pragma unroll
                    for (int j = 0; j < 8; ++j) {
                        float a = ((unsigned)t       < 16384u) ? xb[j*16384 + t    ] : 0.f;
                        float c = ((unsigned)(t + 1) < 16384u) ? xb[j*16384 + t + 1] : 0.f;
                        xv[it*8 + j] = make_float2(a, c);
                    }
                }
            }
        }
        if (tid < 128) bias_lds[tid] = bias[(size_t)b*8192 + tid*64 + f];
    }
    __builtin_amdgcn_sched_barrier(0);

    // ---- A2: issue aw loads (needed in B) ----
    uint4v aw[6];
    #pragma unroll
    for (int kk = 0; kk < 6; ++kk) {
        int w0 = kk*1024 + mt*64 + ln;                 // jp stride 256
        aw[kk].x = wf[w0      ]; aw[kk].y = wf[w0 + 256];
        aw[kk].z = wf[w0 + 512]; aw[kk].w = wf[w0 + 768];
    }
    __builtin_amdgcn_sched_barrier(0);

    // ---- A3: convert x -> xt (lrelu, bf16, swizzled); frees xv regs ----
    #pragma unroll
    for (int it = 0; it < 3; ++it) {
        if (it < 2 || ln < 16) {
            int p0 = 2*ln + it*128;
            unsigned int w0[4], w1[4];
            #pragma unroll
            for (int jq = 0; jq < 4; ++jq) {
                float2 e0 = xv[it*8 + 2*jq], e1 = xv[it*8 + 2*jq + 1];
                w0[jq] = pack2(lrelu(e0.x), lrelu(e1.x));
                w1[jq] = pack2(lrelu(e0.y), lrelu(e1.y));
            }
            int a0 = ( p0     *128 + g*16) ^ (( p0      & 7) << 4);
            int a1 = ((p0 + 1)*128 + g*16) ^ (((p0 + 1) & 7) << 4);
            *(uint4*)(lds + a0) = make_uint4(w0[0], w0[1], w0[2], w0[3]);
            *(uint4*)(lds + a1) = make_uint4(w1[0], w1[1], w1[2], w1[3]);
        }
    }
    __builtin_amdgcn_sched_barrier(0);

    // ---- A4: issue am loads (needed in C; latency hides under B) ----
    uint4v am0[6], am1[6];
    {
        const unsigned int* kp = ktf + (size_t)blk * 12288;
        #pragma unroll
        for (int kk = 0; kk < 6; ++kk) {
            int b0 = kk*2048 + mt*64 + ln;             // jp stride 512, mt stride 64
            am0[kk].x = kp[b0      ]; am0[kk].y = kp[b0 +  512];
            am0[kk].z = kp[b0 + 1024]; am0[kk].w = kp[b0 + 1536];
            int b1 = b0 + 256;                         // mt + 4
            am1[kk].x = kp[b1      ]; am1[kk].y = kp[b1 +  512];
            am1[kk].z = kp[b1 + 1024]; am1[kk].w = kp[b1 + 1536];
        }
    }
    __syncthreads();

    // ---- Phase B: dilated conv via MFMA; wave (mt, nth); writes ht ----
    {
        float4 cb4 = *(const float4*)(conv_b + mt*16 + hi*4);
        const int n0  = nth ? 9 : 0;
        const int cnt = nth ? 8 : 9;                   // nt 0..8 | 9..16
        int bqa[6];
        #pragma unroll
        for (int kk = 0; kk < 6; ++kk) {
            int row = n0*16 + lo + 3*(kk >> 1) + 1;    // row&7 invariant across nt
            int cib = (kk & 1)*32 + hi*8;
            bqa[kk] = (row*128 + cib*2) ^ ((row & 7) << 4);
        }
        int hta  = 36864 + (((n0*16 + lo)*128 + (mt*16 + hi*4)*2) ^ ((lo & 7) << 4));
        int pos  = t0 + n0*16 + lo - 8;
        #pragma unroll 1
        for (int i = 0; i < cnt; ++i) {
            short8 bq[6];
            #pragma unroll
            for (int kk = 0; kk < 6; ++kk)
                bq[kk] = *(const short8*)(lds + bqa[kk]);
            f32x4 acc = {0.f, 0.f, 0.f, 0.f};
            __builtin_amdgcn_s_setprio(1);
            #pragma unroll
            for (int kk = 0; kk < 6; ++kk)
                acc = __builtin_amdgcn_mfma_f32_16x16x32_bf16(
                        __builtin_bit_cast(short8, aw[kk]), bq[kk], acc, 0, 0, 0);
            __builtin_amdgcn_s_setprio(0);

            bool valid = (unsigned)pos < 16384u;
            unsigned int h01 = valid ? pack2(lrelu(acc[0] + cb4.x), lrelu(acc[1] + cb4.y)) : 0u;
            unsigned int h23 = valid ? pack2(lrelu(acc[2] + cb4.z), lrelu(acc[3] + cb4.w)) : 0u;
            unsigned int* d = (unsigned int*)(lds + hta);
            d[0] = h01; d[1] = h23;

            #pragma unroll
            for (int kk = 0; kk < 6; ++kk) bqa[kk] += 2048;
            hta += 2048; pos += 16;
        }
    }
    __syncthreads();

    // ---- Phase C: LVC via MFMA; wave (mt,nth) owns oc-tiles {mt, mt+4} ----
    {
        float ba[4], bb[4];
        size_t rowbase[4];
        #pragma unroll
        for (int r = 0; r < 4; ++r) {
            int c = mt*16 + hi*4 + r;
            ba[r] = bias_lds[c];
            bb[r] = bias_lds[c + 64];
            rowbase[r] = (size_t)(b*64 + c)*16384 + t0 + nth*128 + lo;
        }
        int bqa[6];
        #pragma unroll
        for (int kk = 0; kk < 6; ++kk) {
            int row = nth*128 + lo + (kk >> 1) + 7;    // row&7 invariant across i
            int cib = (kk & 1)*32 + hi*8;
            bqa[kk] = 36864 + ((row*128 + cib*2) ^ ((row & 7) << 4));
        }
        int prow = nth*128 + lo + 12;
        int ra   = (prow*128 + (mt*16 + hi*4)*2) ^ ((prow & 7) << 4);

        #pragma unroll 1
        for (int i = 0; i < 8; ++i) {
            short8 bq[6];
            #pragma unroll
            for (int kk = 0; kk < 6; ++kk)
                bq[kk] = *(const short8*)(lds + bqa[kk]);
            // residual from live xt tile (lrelu is invertible)
            uint2 rv = *(const uint2*)(lds + ra);

            f32x4 a0 = {0.f,0.f,0.f,0.f}, a1 = {0.f,0.f,0.f,0.f};
            __builtin_amdgcn_s_setprio(1);
            #pragma unroll
            for (int kk = 0; kk < 6; ++kk) {
                a0 = __builtin_amdgcn_mfma_f32_16x16x32_bf16(
                        __builtin_bit_cast(short8, am0[kk]), bq[kk], a0, 0, 0, 0);
                a1 = __builtin_amdgcn_mfma_f32_16x16x32_bf16(
                        __builtin_bit_cast(short8, am1[kk]), bq[kk], a1, 0, 0, 0);
            }
            __builtin_amdgcn_s_setprio(0);

            #pragma unroll
            for (int r = 0; r < 4; ++r) {
                unsigned int u = (r < 2 ? rv.x : rv.y) >> ((r & 1) * 16);
                float hv = bf2f(u & 0xFFFFu);
                float xr = hv > 0.f ? hv : 5.0f * hv;  // inverse lrelu
                float gg = glu_gate(a0[r] + ba[r], a1[r] + bb[r]);
                out[rowbase[r] + (size_t)i*16] = xr + gg;
            }
            #pragma unroll
            for (int kk = 0; kk < 6; ++kk) bqa[kk] += 2048;
            ra += 2048;
        }
    }
}

extern "C" void kernel_launch(void* const* d_in, const int* in_sizes, int n_in,
                              void* d_out, int out_size, void* d_ws, size_t ws_size,
                              hipStream_t stream)
{
    const float* x      = (const float*)d_in[0];
    const float* kern   = (const float*)d_in[1];
    const float* bias   = (const float*)d_in[2];
    const float* conv_b = (const float*)d_in[4];
    float* out = (float*)d_out;

    if (ws_size < WS_NEED) return;   // harness provides >=100MB (verified R0)

    unsigned int* ktf = (unsigned int*)d_ws;
    unsigned int* wf  = (unsigned int*)((char*)d_ws + KTF_BYTES);

    wf_prep      <<<dim3(24),   dim3(TB), 0, stream>>>((const float*)d_in[3], wf);
    ktf_transpose<<<dim3(1536), dim3(TB), 0, stream>>>(kern, ktf);
    fused_kernel <<<dim3(1024), dim3(512), 0, stream>>>(x, bias, conv_b, ktf, wf, out);
    (void)in_sizes; (void)n_in; (void)out_size;
}